// Round 17
// baseline (359.534 us; speedup 1.0000x reference)
//
#include <hip/hip_runtime.h>

#define S_LEN 77
#define NHEAD 12
#define DHEAD 64
#define EMB   768
#define BATCH 512
#define MROWS (BATCH * S_LEN)   /* 39424 */
#define NQKV  (3 * EMB)         /* 2304  */
#define KDIM  768
#define NKT   (KDIM / 64)       /* 12 K-tiles of 64 */
#define SECSZ (BATCH * NHEAD * S_LEN * DHEAD)   /* 30,277,632 shorts per Q/K/V section */
#define HTILE (S_LEN * DHEAD)   /* 4928 shorts per head tile */

typedef __attribute__((ext_vector_type(8))) short bf16x8;
typedef __attribute__((ext_vector_type(4))) float f32x4;

#define WAITV(n) asm volatile("s_waitcnt vmcnt(" #n ")" ::: "memory")

__device__ __forceinline__ unsigned short f2bf(float f) {
  union { float f; unsigned int u; } v; v.f = f;
  unsigned int r = (v.u + 0x7fffu + ((v.u >> 16) & 1u)) >> 16;
  return (unsigned short)r;
}

__device__ __forceinline__ void gload_lds16(const void* g, void* l) {
  __builtin_amdgcn_global_load_lds((__attribute__((address_space(1))) void*)g,
                                   (__attribute__((address_space(3))) void*)l,
                                   16, 0, 0);
}

// ---------------- fused: x fp32->bf16 + weight transpose + bias ----------------
__global__ void prep_all(const float4* __restrict__ x4, ushort4* __restrict__ xbf4,
                         const float* __restrict__ wq, const float* __restrict__ wk,
                         const float* __restrict__ wv, const float* __restrict__ wo,
                         const float* __restrict__ bq, const float* __restrict__ bk,
                         const float* __restrict__ bv,
                         unsigned short* __restrict__ wqkvT,
                         unsigned short* __restrict__ woT,
                         float* __restrict__ bqkv) {
  const int i0 = blockIdx.x * blockDim.x + threadIdx.x;
  const int stride = gridDim.x * blockDim.x;
  const int KB = EMB / 8;   // 96 eight-wide k-blocks per row
  for (int idx = i0; idx < NQKV * KB; idx += stride) {
    int n = idx / KB, k0 = (idx - n * KB) * 8;
    const float* w; int c;
    if (n < EMB)          { w = wq; c = n; }
    else if (n < 2 * EMB) { w = wk; c = n - EMB; }
    else                  { w = wv; c = n - 2 * EMB; }
    bf16x8 o;
#pragma unroll
    for (int i = 0; i < 8; ++i) o[i] = (short)f2bf(w[(size_t)(k0 + i) * EMB + c]);
    *(bf16x8*)(wqkvT + (size_t)n * EMB + k0) = o;
  }
  for (int idx = i0; idx < EMB * KB; idx += stride) {
    int n = idx / KB, k0 = (idx - n * KB) * 8;
    bf16x8 o;
#pragma unroll
    for (int i = 0; i < 8; ++i) o[i] = (short)f2bf(wo[(size_t)(k0 + i) * EMB + n]);
    *(bf16x8*)(woT + (size_t)n * EMB + k0) = o;
  }
  for (int idx = i0; idx < NQKV; idx += stride) {
    bqkv[idx] = (idx < EMB) ? bq[idx]
              : (idx < 2 * EMB ? bk[idx - EMB] : bv[idx - 2 * EMB]);
  }
  for (int i = i0; i < MROWS * EMB / 4; i += stride) {
    float4 v = x4[i];
    ushort4 o;
    o.x = f2bf(v.x); o.y = f2bf(v.y); o.z = f2bf(v.z); o.w = f2bf(v.w);
    xbf4[i] = o;
  }
}

// ---------------- 256x256 8-phase-style GEMM (round-5 loop, known-good) ----
// MODE 0: A = x_bf row-major [M][768]; C -> head-major sections sec[bh][s][d],
//         Q scaled 0.125, bf16.
// MODE 1: A = attn_o HEAD-MAJOR [bh][77][64] (BK=64 == DHEAD: A-tile t IS head
//         t; per-thread per-round bases precomputed). C = f32 row-major [M][768].
template <int MODE>
__global__ __launch_bounds__(512, 2) void gemm256(const unsigned short* __restrict__ A,
                                                  const unsigned short* __restrict__ BT,
                                                  const float* __restrict__ bias,
                                                  void* __restrict__ Cout) {
  __shared__ unsigned short lds[2 * 32768];   // 128 KiB

  const int tid  = threadIdx.x;
  const int wave = tid >> 6;
  const int lane = tid & 63;
  const int wr = wave >> 2;        // 0..1  -> rows wr*128..+128
  const int wc = wave & 3;         // 0..3  -> cols wc*64..+64
  const int fr = lane & 15;
  const int fg = lane >> 4;        // 0..3

  // T1: bijective XCD swizzle (m204)
  const int ncol = gridDim.x;
  const int nwg  = gridDim.x * gridDim.y;
  const int orig = blockIdx.y * gridDim.x + blockIdx.x;
  const int q8   = nwg >> 3, r8 = nwg & 7;
  const int xcd  = orig & 7, off = orig >> 3;
  const int swz  = (xcd < r8 ? xcd * (q8 + 1) : r8 * (q8 + 1) + (xcd - r8) * q8) + off;
  const int brow = (swz / ncol) * 256;
  const int bcol = (swz % ncol) * 256;

  f32x4 acc[8][4] = {};

  const int grow = (wave >> 2) * 128 + (wave & 3) * 8 + (lane >> 3);
  const int srcc = (lane & 7) ^ ((lane >> 3) & 7);
  const unsigned short* gA = A + (size_t)(brow + grow) * KDIM + srcc * 8;  // MODE 0
  size_t abase[4];                                                          // MODE 1
  if (MODE == 1) {
#pragma unroll
    for (int j = 0; j < 4; ++j) {
      const int row = brow + grow + j * 32;
      const int bb = row / S_LEN;
      const int ss = row - bb * S_LEN;
      abase[j] = (size_t)bb * (NHEAD * HTILE) + (size_t)ss * DHEAD + srcc * 8;
    }
  }
  const unsigned short* gB = BT + (size_t)(bcol + grow) * KDIM + srcc * 8;
  const int wbase = (wave >> 2) * 8192 + (wave & 3) * 512;

  auto ALOAD = [&](int t, int j) {
    if (MODE == 1)
      gload_lds16(A + abase[j] + (size_t)t * HTILE,
                  lds + (t & 1) * 32768 + wbase + j * 2048);
    else
      gload_lds16(gA + (size_t)(j * 32) * KDIM + t * 64,
                  lds + (t & 1) * 32768 + wbase + j * 2048);
  };
  auto BLOAD = [&](int t, int j) {
    gload_lds16(gB + (size_t)(j * 32) * KDIM + t * 64,
                lds + (t & 1) * 32768 + 16384 + wbase + j * 2048);
  };

  const int rsw = fr & 7;          // read-side XOR on the 16B chunk index

  // prologue: stage tile 0 fully (B rounds then A rounds), wait all but A2,A3
  #pragma unroll
  for (int j = 0; j < 4; ++j) BLOAD(0, j);
  #pragma unroll
  for (int j = 0; j < 4; ++j) ALOAD(0, j);
  WAITV(2);
  __builtin_amdgcn_sched_barrier(0);
  __builtin_amdgcn_s_barrier();

  for (int t = 0; t < NKT; ++t) {
    const bool st = (t + 1 < NKT);             // stage tile t+1 this group
    const unsigned short* sb  = lds + (t & 1) * 32768;
    const unsigned short* sbB = sb + 16384;
    bf16x8 bfr[4][2];
    #pragma unroll
    for (int p = 0; p < 4; ++p) {
      if (p == 0) {
        #pragma unroll
        for (int n = 0; n < 4; ++n)
          #pragma unroll
          for (int kk = 0; kk < 2; ++kk)
            bfr[n][kk] = *(const bf16x8*)(sbB + (wc * 64 + n * 16 + fr) * 64 +
                                          (((kk * 4 + fg) ^ rsw) * 8));
      }
      bf16x8 afr[2][2];
      #pragma unroll
      for (int mi = 0; mi < 2; ++mi)
        #pragma unroll
        for (int kk = 0; kk < 2; ++kk)
          afr[mi][kk] = *(const bf16x8*)(sb + (wr * 128 + (2 * p + mi) * 16 + fr) * 64 +
                                         (((kk * 4 + fg) ^ rsw) * 8));
      if (st) {
        if (p < 2) { BLOAD(t + 1, 2 * p);     BLOAD(t + 1, 2 * p + 1); }
        else       { ALOAD(t + 1, 2 * p - 4); ALOAD(t + 1, 2 * p - 3); }
      }
      __builtin_amdgcn_sched_barrier(0);
      __builtin_amdgcn_s_barrier();
      asm volatile("s_waitcnt lgkmcnt(0)" ::: "memory");
      __builtin_amdgcn_sched_barrier(0);
      __builtin_amdgcn_s_setprio(1);
      #pragma unroll
      for (int kk = 0; kk < 2; ++kk)
        #pragma unroll
        for (int mi = 0; mi < 2; ++mi)
          #pragma unroll
          for (int n = 0; n < 4; ++n)
            acc[2 * p + mi][n] = __builtin_amdgcn_mfma_f32_16x16x32_bf16(
                afr[mi][kk], bfr[n][kk], acc[2 * p + mi][n], 0, 0, 0);
      __builtin_amdgcn_s_setprio(0);
      __builtin_amdgcn_sched_barrier(0);
      if (p == 1) { if (st) { WAITV(4); } else { WAITV(0); } }
      if (p == 3 && st) { WAITV(2); }
      __builtin_amdgcn_s_barrier();
    }
  }

  // epilogue
  float bvals[4];
#pragma unroll
  for (int n = 0; n < 4; ++n) bvals[n] = bias[bcol + wc * 64 + n * 16 + fr];

  if (MODE == 0) {
    const int h64 = (bcol + wc * 64) >> 6;      // 0..35
    const int sec = h64 / NHEAD;                // 0:Q 1:K 2:V
    const int hh  = h64 - sec * NHEAD;
    const float scale = (sec == 0) ? 0.125f : 1.0f;
    unsigned short* outb = (unsigned short*)Cout + (size_t)sec * SECSZ;
#pragma unroll
    for (int m = 0; m < 8; ++m) {
#pragma unroll
      for (int r = 0; r < 4; ++r) {
        const int row = brow + wr * 128 + m * 16 + fg * 4 + r;
        const int bb = row / S_LEN;             // const-divide -> magic mul
        const int ss = row - bb * S_LEN;
        const size_t rbase = ((size_t)(bb * NHEAD + hh) * S_LEN + ss) * DHEAD;
#pragma unroll
        for (int n = 0; n < 4; ++n)
          outb[rbase + n * 16 + fr] = f2bf((acc[m][n][r] + bvals[n]) * scale);
      }
    }
  } else {
#pragma unroll
    for (int m = 0; m < 8; ++m) {
#pragma unroll
      for (int r = 0; r < 4; ++r) {
        const int row = brow + wr * 128 + m * 16 + fg * 4 + r;
#pragma unroll
        for (int n = 0; n < 4; ++n) {
          const int col = bcol + wc * 64 + n * 16 + fr;
          ((float*)Cout)[(size_t)row * EMB + col] = acc[m][n][r] + bvals[n];
        }
      }
    }
  }
}

// ---------------- attention: one block per (b,h), 5 waves (16-row stripes) ----
// Round-15 best: head-major in/out, Q/K direct to regs, V transposed via LDS,
// no-max-sub softmax, LDS-staged contiguous output stores.
#define SV 104
__global__ __launch_bounds__(320) void attn_kernel(const unsigned short* __restrict__ qkv,
                                                   unsigned short* __restrict__ attn_out) {
  __shared__ unsigned short vT_lds[64 * SV];   // [d][t] stride 104; reused as out-stage
  __shared__ unsigned short p_lds[80 * SV];    // [s][t], stride 104

  const int tid  = threadIdx.x;
  const int wv_  = tid >> 6;   // stripe 0..4
  const int lane = tid & 63;
  const int fr = lane & 15;
  const int fg = lane >> 4;

  const int bh = blockIdx.x;

  const unsigned short* Qb = qkv;
  const unsigned short* Kb = qkv + SECSZ;
  const unsigned short* Vb = qkv + 2 * (size_t)SECSZ;
  const size_t hbase = (size_t)bh * HTILE;     // head tile base (in shorts)

  // Q fragments (this stripe's rows) + K fragments (all t rows) direct to regs
  bf16x8 qfr[2], kfr[5][2];
  {
    const int srow = wv_ * 16 + fr;
    const int qs = (srow < S_LEN) ? srow : 0;   // clamp: pad rows discarded later
    const unsigned short* qg = Qb + hbase + qs * DHEAD + fg * 8;
    qfr[0] = *(const bf16x8*)(qg);
    qfr[1] = *(const bf16x8*)(qg + 32);
    const unsigned short* kg = Kb + hbase + fg * 8;
#pragma unroll
    for (int n = 0; n < 5; ++n)
#pragma unroll
      for (int kk = 0; kk < 2; ++kk)
        kfr[n][kk] = *(const bf16x8*)(kg + (n * 16 + fr) * DHEAD + kk * 32);
    // t=77..79 for the last head reads past Kb into Vb: in-bounds, masked.
  }

  // zero ONLY the pad strips PV multiplies by nonzero values
  for (int i = tid; i < 64 * 19; i += 320) {
    int d = i / 19, c = 77 + (i - d * 19);
    vT_lds[d * SV + c] = 0;
  }
  for (int i = tid; i < 80 * 16; i += 320) {
    int s = i >> 4, c = 80 + (i & 15);
    p_lds[s * SV + c] = 0;
  }

  // stage transposed V: contiguous 128B row reads
  for (int idx = tid; idx < S_LEN * 32; idx += 320) {
    int s = idx >> 5, c = idx & 31;
    unsigned int vx = *(const unsigned int*)(Vb + hbase + s * DHEAD + c * 2);
    vT_lds[(c * 2 + 0) * SV + s] = (unsigned short)(vx & 0xffffu);
    vT_lds[(c * 2 + 1) * SV + s] = (unsigned short)(vx >> 16);
  }

  // QK^T : scores[s][t] from registers only — no barrier needed
  f32x4 sc[5];
#pragma unroll
  for (int n = 0; n < 5; ++n) sc[n] = (f32x4){0.f, 0.f, 0.f, 0.f};
#pragma unroll
  for (int kk = 0; kk < 2; ++kk)
#pragma unroll
    for (int n = 0; n < 5; ++n)
      sc[n] = __builtin_amdgcn_mfma_f32_16x16x32_bf16(qfr[kk], kfr[n][kk], sc[n], 0, 0, 0);

  // softmax, no max-subtraction: p = (t<=s) ? exp(score) : 0
  float ssum[4] = {0.f, 0.f, 0.f, 0.f};
#pragma unroll
  for (int n = 0; n < 5; ++n) {
    const int t = n * 16 + fr;
#pragma unroll
    for (int r = 0; r < 4; ++r) {
      const int s_loc = wv_ * 16 + fg * 4 + r;
      float p = ((t <= s_loc) && (t < S_LEN)) ? __expf(sc[n][r]) : 0.0f;
      sc[n][r] = p;
      ssum[r] += p;
    }
  }
#pragma unroll
  for (int off = 1; off < 16; off <<= 1)
#pragma unroll
    for (int r = 0; r < 4; ++r)
      ssum[r] += __shfl_xor(ssum[r], off, 64);

#pragma unroll
  for (int r = 0; r < 4; ++r) {
    const int srow = wv_ * 16 + fg * 4 + r;
    const float inv = 1.0f / ssum[r];
#pragma unroll
    for (int n = 0; n < 5; ++n)
      p_lds[srow * SV + n * 16 + fr] = f2bf(sc[n][r] * inv);
  }
  // barrier: vT (cross-wave) + p (wave-local) both complete before PV
  __syncthreads();

  // PV : out[s][d] = sum_t p[s][t] * v[t][d], t padded to 96 (pad strips zero)
  f32x4 o[4];
#pragma unroll
  for (int n = 0; n < 4; ++n) o[n] = (f32x4){0.f, 0.f, 0.f, 0.f};
#pragma unroll
  for (int kk = 0; kk < 96; kk += 32) {
    bf16x8 afr = *(const bf16x8*)(p_lds + (wv_ * 16 + fr) * SV + kk + fg * 8);
#pragma unroll
    for (int n = 0; n < 4; ++n) {
      bf16x8 bfr = *(const bf16x8*)(vT_lds + (n * 16 + fr) * SV + kk + fg * 8);
      o[n] = __builtin_amdgcn_mfma_f32_16x16x32_bf16(afr, bfr, o[n], 0, 0, 0);
    }
  }

  // stage output through LDS (vT_lds dead after PV) -> contiguous 16B stores
  __syncthreads();                               // all waves done reading vT
  unsigned short* stage = vT_lds;                // [80][64]
#pragma unroll
  for (int r = 0; r < 4; ++r) {
    const int srow = wv_ * 16 + fg * 4 + r;
#pragma unroll
    for (int n = 0; n < 4; ++n)
      stage[srow * DHEAD + n * 16 + fr] = f2bf(o[n][r]);
  }
  __syncthreads();
  unsigned short* outp = attn_out + hbase;       // head-major [bh][77][64]
  for (int i = tid; i < HTILE / 8; i += 320)     // 616 x 16B contiguous
    *(bf16x8*)(outp + i * 8) = *(const bf16x8*)(stage + i * 8);
}

extern "C" void kernel_launch(void* const* d_in, const int* in_sizes, int n_in,
                              void* d_out, int out_size, void* d_ws, size_t ws_size,
                              hipStream_t stream) {
  const float* x  = (const float*)d_in[0];
  const float* wq = (const float*)d_in[1];
  const float* bq = (const float*)d_in[2];
  const float* wk = (const float*)d_in[3];
  const float* bk = (const float*)d_in[4];
  const float* wv = (const float*)d_in[5];
  const float* bv = (const float*)d_in[6];
  const float* wo = (const float*)d_in[7];
  const float* bo = (const float*)d_in[8];
  (void)in_sizes; (void)n_in; (void)out_size; (void)ws_size;

  char* ws = (char*)d_ws;
  // layout (bytes):
  unsigned short* x_bf   = (unsigned short*)(ws);                  // M*E bf16      = 60,555,264
  unsigned short* wqkvT  = (unsigned short*)(ws + 60555264ULL);    // 2304*768 bf16 =  3,538,944
  unsigned short* woT    = (unsigned short*)(ws + 64094208ULL);    // 768*768 bf16  =  1,179,648
  float*          bqkv   = (float*)         (ws + 65273856ULL);    // 2304 f32      =      9,216
  unsigned short* qkv    = (unsigned short*)(ws + 65283072ULL);    // 3 sections    = 181,665,792
  unsigned short* attn_o = (unsigned short*)(ws + 246948864ULL);   // head-major    = 60,555,264

  prep_all<<<2048, 256, 0, stream>>>((const float4*)x, (ushort4*)x_bf,
                                     wq, wk, wv, wo, bq, bk, bv, wqkvT, woT, bqkv);
  gemm256<0><<<dim3(NQKV / 256, MROWS / 256), 512, 0, stream>>>(x_bf, wqkvT, bqkv, qkv);
  attn_kernel<<<BATCH * NHEAD, 320, 0, stream>>>(qkv, attn_o);
  gemm256<1><<<dim3(EMB / 256, MROWS / 256), 512, 0, stream>>>(attn_o, woT, bo, d_out);
}